// Round 5
// baseline (2846.627 us; speedup 1.0000x reference)
//
#include <hip/hip_runtime.h>
#include <stdint.h>

#define B_ 16
#define S_ 2048
#define F_ 129
#define H_ 128
#define G_ 512   // 4*H

typedef float f32x4 __attribute__((ext_vector_type(4)));
typedef float f32x2 __attribute__((ext_vector_type(2)));
typedef short s16x8 __attribute__((ext_vector_type(8)));
typedef _Float16 h2_t __attribute__((ext_vector_type(2)));

// LDS-only barrier: waits ds ops, does NOT drain vmcnt (global loads/stores
// stay in flight across it). __syncthreads() would emit s_waitcnt vmcnt(0)
// -> per-step store-ack/load drain, the round-3/4 hidden cost.
#define BAR_LDS() __asm__ volatile("s_waitcnt lgkmcnt(0)\n\ts_barrier" ::: "memory")

__device__ inline unsigned short f2bf(float f) {
  union { float f; unsigned u; } v; v.f = f;
  unsigned u = v.u;
  unsigned r = (u + 0x7FFFu + ((u >> 16) & 1u)) >> 16;
  return (unsigned short)r;
}

__device__ inline float rcp_(float x) { return __builtin_amdgcn_rcpf(x); }

__device__ inline float tanh_fast(float x) {
  float t = __expf(-2.f * fabsf(x));
  float r = (1.f - t) * rcp_(1.f + t);
  return x >= 0.f ? r : -r;
}

__device__ inline float dot2_acc(h2_t a, h2_t b, float c) {
#if __has_builtin(__builtin_amdgcn_fdot2)
  return __builtin_amdgcn_fdot2(a, b, c, false);
#else
  return c + (float)a.x * (float)b.x + (float)a.y * (float)b.y;
#endif
}

// ---------------------------------------------------------------------------
// xg[b,s,g] = sum_f x[b,s,f] * W_ih[g,f] + b_ih[g]
// ---------------------------------------------------------------------------
__global__ __launch_bounds__(256) void xg_kernel(const float* __restrict__ x,
    const float* __restrict__ W_ih, const float* __restrict__ b_ih,
    float* __restrict__ xg) {
  __shared__ __align__(16) float xs[64 * 132];
  __shared__ __align__(16) float ws[32 * 132];
  int tid = threadIdx.x;
  long R0 = (long)blockIdx.x * 64;
  for (int i = tid; i < 64 * 129; i += 256) {
    int r = i / 129, c = i - r * 129;
    xs[r * 132 + c] = x[R0 * 129 + i];
  }
  int cl = tid & 31, rg = tid >> 5;
  int r0 = rg * 8;
  for (int ch = 0; ch < 16; ++ch) {
    __syncthreads();
    for (int i = tid; i < 32 * 129; i += 256) {
      int r = i / 129, c = i - r * 129;
      ws[r * 132 + c] = W_ih[(ch * 32 + r) * 129 + c];
    }
    __syncthreads();
    int gcol = ch * 32 + cl;
    float bias = b_ih[gcol];
    float acc[8];
    #pragma unroll
    for (int rr = 0; rr < 8; ++rr) acc[rr] = bias;
    const float* wr = &ws[cl * 132];
    #pragma unroll 8
    for (int k = 0; k < 128; k += 4) {
      f32x4 w4 = *(const f32x4*)&wr[k];
      #pragma unroll
      for (int rr = 0; rr < 8; ++rr) {
        f32x4 x4 = *(const f32x4*)&xs[(r0 + rr) * 132 + k];
        acc[rr] += x4.x * w4.x + x4.y * w4.y + x4.z * w4.z + x4.w * w4.w;
      }
    }
    float wl = wr[128];
    #pragma unroll
    for (int rr = 0; rr < 8; ++rr) {
      acc[rr] += xs[(r0 + rr) * 132 + 128] * wl;
      xg[(R0 + r0 + rr) * G_ + gcol] = acc[rr];
    }
  }
}

// ---------------------------------------------------------------------------
// RBF: kf[row] = exp(-sum_f (x-p)^2), one wave per row.
// ---------------------------------------------------------------------------
__global__ __launch_bounds__(256) void rbf_kernel(const float* __restrict__ x,
    const float* __restrict__ p, float* __restrict__ kf) {
  int wave = threadIdx.x >> 6, lane = threadIdx.x & 63;
  long row = (long)blockIdx.x * 4 + wave;
  const float* xr = x + row * F_;
  const float* pr = p + row * F_;
  float ss = 0.f;
  for (int k = lane; k < F_; k += 64) { float d = xr[k] - pr[k]; ss += d * d; }
  #pragma unroll
  for (int off = 32; off; off >>= 1) ss += __shfl_xor(ss, off, 64);
  if (lane == 0) kf[row] = __expf(-ss);
}

// ---------------------------------------------------------------------------
// LSTM scan, round 5. Round-3 dataflow (readlane broadcast + fdot2, lanes
// 0-31 rows (i,g) / lanes 32-63 rows (f,o), h packed-f16 double-buffered in
// LDS) with three changes driven by the round-3/4 barrier-drain finding:
//  (1) BAR_LDS(): lgkmcnt-only barrier -- no vmcnt(0) drain of the qbf store
//      ack (~200-400 cyc) and xg prefetch every step.
//  (2) qbf store delayed one step, issued right after the barrier -> a full
//      step in flight before anything could wait on it.
//  (3) 2 batches per block (8 blocks x 8 waves, 2 waves/SIMD, independent
//      wave-quads) so co-resident waves hide LDS-read/activation latency.
// ---------------------------------------------------------------------------
__global__ __launch_bounds__(512, 2) void lstm_kernel(const float* __restrict__ xg,
    const float* __restrict__ W_hh, const float* __restrict__ b_hh,
    unsigned short* __restrict__ qbf) {
  __shared__ unsigned int hbuf[2][2][64];   // [batch-in-block][dbuf][h as f16x2]
  int tid = threadIdx.x;
  int w = tid >> 6, lane = tid & 63;
  int q = w >> 2;                    // batch within block (wave-quad)
  int w4 = w & 3;
  int sub = lane >> 5;               // 0: rows (i,g)  1: rows (f,o)
  int u = (w4 << 5) | (lane & 31);   // h-unit 0..127
  int r0 = u + (sub << 7);           // i (sub0) / f (sub1)
  int r1 = r0 + 256;                 // g (sub0) / o (sub1)
  int b = blockIdx.x * 2 + q;
  h2_t W0[64], W1[64];
  const float* wr0 = &W_hh[r0 * H_];
  const float* wr1 = &W_hh[r1 * H_];
  #pragma unroll
  for (int k = 0; k < 64; ++k) {     // full unroll: constant indices -> VGPRs
    f32x2 a = *(const f32x2*)&wr0[2 * k];
    f32x2 b2 = *(const f32x2*)&wr1[2 * k];
    W0[k] = h2_t{(_Float16)a.x, (_Float16)a.y};
    W1[k] = h2_t{(_Float16)b2.x, (_Float16)b2.y};
  }
  float b0 = b_hh[r0], b1 = b_hh[r1];
  if (tid < 128) {
    int qq = tid >> 6, ii = tid & 63;
    hbuf[qq][0][ii] = 0u; hbuf[qq][1][ii] = 0u;
  }
  float c = 0.f;
  const float* xgb = xg + (long)b * S_ * G_;
  unsigned short* qb = qbf + (long)b * S_ * H_;
  float cur0 = xgb[r0], cur1 = xgb[r1];
  float nxt0 = xgb[G_ + r0], nxt1 = xgb[G_ + r1];
  unsigned short hv_prev = 0;
  __syncthreads();                   // init visibility (once)
  for (int t = 0; t < S_; ++t) {
    BAR_LDS();                       // h_{t-1} LDS writes visible; no vm drain
    unsigned int hdw = hbuf[q][(t + 1) & 1][lane];
    if (sub == 0 && t > 0)           // delayed store: full step in flight
      qb[(long)(t - 1) * H_ + u] = hv_prev;
    long pf = (long)((t + 2 < S_) ? t + 2 : S_ - 1) * G_;
    float nn0 = xgb[pf + r0], nn1 = xgb[pf + r1];
    float a0c[4] = {cur0 + b0, 0.f, 0.f, 0.f};
    float a1c[4] = {cur1 + b1, 0.f, 0.f, 0.f};
    #pragma unroll
    for (int k = 0; k < 64; ++k) {
      int sdw = __builtin_amdgcn_readlane((int)hdw, k);
      h2_t hp = __builtin_bit_cast(h2_t, sdw);
      a0c[k & 3] = dot2_acc(W0[k], hp, a0c[k & 3]);
      a1c[k & 3] = dot2_acc(W1[k], hp, a1c[k & 3]);
    }
    float g0 = (a0c[0] + a0c[1]) + (a0c[2] + a0c[3]);
    float g1 = (a1c[0] + a1c[1]) + (a1c[2] + a1c[3]);
    float a0 = rcp_(1.f + __expf(-g0));                     // i (sub0) / f (sub1)
    float a1 = sub ? rcp_(1.f + __expf(-g1)) : tanh_fast(g1); // g (sub0) / o (sub1)
    float fo0 = __shfl_xor(a0, 32, 64);                     // f at sub0 lanes
    float fo1 = __shfl_xor(a1, 32, 64);                     // o at sub0 lanes
    if (sub == 0) {
      c = fo0 * c + a0 * a1;
      float hv = fo1 * tanh_fast(c);
      ((_Float16*)hbuf[q][t & 1])[u] = (_Float16)hv;
      hv_prev = f2bf(hv);
    }
    cur0 = nxt0; cur1 = nxt1; nxt0 = nn0; nxt1 = nn1;
  }
  if (sub == 0) qb[(long)(S_ - 1) * H_ + u] = hv_prev;
}

// ---------------------------------------------------------------------------
// Flash attention, scale 1/sqrt(129). 64 Q-rows per block (4 waves x 16 rows),
// KV tiles of 64, bf16 MFMA 16x16x32. Grid = 16 batches * 32 q-tiles.
// ---------------------------------------------------------------------------
__global__ __launch_bounds__(256) void attn_kernel(const unsigned short* __restrict__ qbf,
    float* __restrict__ ctx) {
  __shared__ __align__(16) unsigned short Ks[64 * 136];
  __shared__ __align__(16) unsigned short VT[128 * 72];
  __shared__ __align__(16) unsigned short Ps[4 * 16 * 72];
  int tid = threadIdx.x;
  int lane = tid & 63, w = tid >> 6;
  int b = blockIdx.x >> 5;
  int q0 = (blockIdx.x & 31) * 64;
  const unsigned short* qb = qbf + (long)b * S_ * H_;
  int l15 = lane & 15;
  int koff = (lane >> 4) * 8;
  s16x8 qfrag[4];
  #pragma unroll
  for (int kb = 0; kb < 4; ++kb)
    qfrag[kb] = *(const s16x8*)(qb + (long)(q0 + w * 16 + l15) * H_ + kb * 32 + koff);
  f32x4 oacc[8];
  #pragma unroll
  for (int n = 0; n < 8; ++n)
    #pragma unroll
    for (int r = 0; r < 4; ++r) oacc[n][r] = 0.f;
  float mrow[4], lrow[4];
  #pragma unroll
  for (int r = 0; r < 4; ++r) { mrow[r] = -1e30f; lrow[r] = 0.f; }
  const float scale = 0.08804509063256238f;  // 1/sqrt(129)
  unsigned short* Pw = &Ps[w * 16 * 72];
  for (int t = 0; t < S_ / 64; ++t) {
    {
      int rr = tid >> 4;
      int c0 = (tid & 15) * 8;
      #pragma unroll
      for (int pch = 0; pch < 4; ++pch) {
        int r = pch * 16 + rr;
        s16x8 v = *(const s16x8*)(qb + (long)(t * 64 + r) * H_ + c0);
        *(s16x8*)(&Ks[r * 136 + c0]) = v;
        #pragma unroll
        for (int i = 0; i < 8; ++i) VT[(c0 + i) * 72 + r] = (unsigned short)v[i];
      }
    }
    __syncthreads();
    f32x4 sacc[4];
    #pragma unroll
    for (int n = 0; n < 4; ++n) {
      f32x4 acc;
      #pragma unroll
      for (int r = 0; r < 4; ++r) acc[r] = 0.f;
      #pragma unroll
      for (int kb = 0; kb < 4; ++kb) {
        s16x8 bfrag = *(const s16x8*)(&Ks[(n * 16 + l15) * 136 + kb * 32 + koff]);
        acc = __builtin_amdgcn_mfma_f32_16x16x32_bf16(qfrag[kb], bfrag, acc, 0, 0, 0);
      }
      sacc[n] = acc;
    }
    #pragma unroll
    for (int r = 0; r < 4; ++r) {
      float mx = fmaxf(fmaxf(sacc[0][r], sacc[1][r]), fmaxf(sacc[2][r], sacc[3][r]));
      #pragma unroll
      for (int m = 1; m < 16; m <<= 1) mx = fmaxf(mx, __shfl_xor(mx, m, 64));
      mx *= scale;
      float mnew = fmaxf(mrow[r], mx);
      float alpha = __expf(mrow[r] - mnew);
      mrow[r] = mnew;
      float psum = 0.f;
      #pragma unroll
      for (int n = 0; n < 4; ++n) {
        float pv = __expf(sacc[n][r] * scale - mnew);
        sacc[n][r] = pv;
        psum += pv;
      }
      #pragma unroll
      for (int m = 1; m < 16; m <<= 1) psum += __shfl_xor(psum, m, 64);
      lrow[r] = lrow[r] * alpha + psum;
      #pragma unroll
      for (int n = 0; n < 8; ++n) oacc[n][r] *= alpha;
    }
    #pragma unroll
    for (int n = 0; n < 4; ++n)
      #pragma unroll
      for (int r = 0; r < 4; ++r)
        Pw[((lane >> 4) * 4 + r) * 72 + n * 16 + l15] = f2bf(sacc[n][r]);
    __syncthreads();
    #pragma unroll
    for (int kb = 0; kb < 2; ++kb) {
      s16x8 afrag = *(const s16x8*)(&Pw[l15 * 72 + kb * 32 + koff]);
      #pragma unroll
      for (int n = 0; n < 8; ++n) {
        s16x8 bfrag = *(const s16x8*)(&VT[(n * 16 + l15) * 72 + kb * 32 + koff]);
        oacc[n] = __builtin_amdgcn_mfma_f32_16x16x32_bf16(afrag, bfrag, oacc[n], 0, 0, 0);
      }
    }
    __syncthreads();
  }
  float* cb = ctx + (long)b * S_ * H_;
  #pragma unroll
  for (int n = 0; n < 8; ++n)
    #pragma unroll
    for (int r = 0; r < 4; ++r) {
      int row = q0 + w * 16 + (lane >> 4) * 4 + r;
      cb[(long)row * H_ + n * 16 + l15] = oacc[n][r] / lrow[r];
    }
}

// ---------------------------------------------------------------------------
// Fused MLP: h0=[ctx,kf] -> 4x relu(h W^T + b) -> logits -> log_softmax.
// ---------------------------------------------------------------------------
__global__ __launch_bounds__(256) void mlp_kernel(const float* __restrict__ ctx,
    const float* __restrict__ kf, const float* __restrict__ Wc,
    const float* __restrict__ bc, const float* __restrict__ Wh,
    const float* __restrict__ bh, float* __restrict__ out) {
  __shared__ __align__(16) float hb[64 * 132];
  __shared__ __align__(16) float wc[32 * 132];
  int tid = threadIdx.x;
  long R0 = (long)blockIdx.x * 64;
  for (int i = tid; i < 64 * 128; i += 256) {
    int r = i >> 7, c = i & 127;
    hb[r * 132 + c] = ctx[(R0 + r) * H_ + c];
  }
  for (int r = tid; r < 64; r += 256) hb[r * 132 + 128] = kf[R0 + r];
  int cl = tid & 31, rg = tid >> 5, r0 = rg * 8;
  for (int l = 0; l < 4; ++l) {
    float areg[5][8];
    #pragma unroll
    for (int cc = 0; cc < 5; ++cc) {
      int cbase = cc * 32;
      int ccnt = (cc < 4) ? 32 : 1;
      __syncthreads();
      for (int i = tid; i < ccnt * 129; i += 256) {
        int r = i / 129, c = i - r * 129;
        wc[r * 132 + c] = Wc[(l * 129 + cbase + r) * 129 + c];
      }
      __syncthreads();
      if (cl < ccnt) {
        float bias = bc[l * 129 + cbase + cl];
        float acc[8];
        #pragma unroll
        for (int rr = 0; rr < 8; ++rr) acc[rr] = bias;
        const float* wr = &wc[cl * 132];
        for (int k = 0; k < 128; k += 4) {
          f32x4 w4 = *(const f32x4*)&wr[k];
          #pragma unroll
          for (int rr = 0; rr < 8; ++rr) {
            f32x4 x4 = *(const f32x4*)&hb[(r0 + rr) * 132 + k];
            acc[rr] += x4.x * w4.x + x4.y * w4.y + x4.z * w4.z + x4.w * w4.w;
          }
        }
        float wl = wr[128];
        #pragma unroll
        for (int rr = 0; rr < 8; ++rr)
          areg[cc][rr] = fmaxf(acc[rr] + hb[(r0 + rr) * 132 + 128] * wl, 0.f);
      }
    }
    __syncthreads();
    #pragma unroll
    for (int cc = 0; cc < 5; ++cc) {
      int ccnt = (cc < 4) ? 32 : 1;
      if (cl < ccnt) {
        #pragma unroll
        for (int rr = 0; rr < 8; ++rr) hb[(r0 + rr) * 132 + cc * 32 + cl] = areg[cc][rr];
      }
    }
    __syncthreads();
  }
  if (tid < 64) {
    int r = tid;
    float z0 = bh[0], z1 = bh[1];
    for (int k = 0; k < 129; ++k) {
      float h = hb[r * 132 + k];
      z0 += h * Wh[k];
      z1 += h * Wh[129 + k];
    }
    float mx = fmaxf(z0, z1);
    float lse = mx + __logf(__expf(z0 - mx) + __expf(z1 - mx));
    out[(R0 + r) * 2 + 0] = z0 - lse;
    out[(R0 + r) * 2 + 1] = z1 - lse;
  }
}

extern "C" void kernel_launch(void* const* d_in, const int* in_sizes, int n_in,
                              void* d_out, int out_size, void* d_ws, size_t ws_size,
                              hipStream_t stream) {
  const float* x    = (const float*)d_in[0];
  const float* prot = (const float*)d_in[1];
  const float* W_ih = (const float*)d_in[2];
  const float* W_hh = (const float*)d_in[3];
  const float* b_ih = (const float*)d_in[4];
  const float* b_hh = (const float*)d_in[5];
  const float* Wc   = (const float*)d_in[6];
  const float* bc   = (const float*)d_in[7];
  const float* Wh   = (const float*)d_in[8];
  const float* bh   = (const float*)d_in[9];
  float* out = (float*)d_out;
  char* ws = (char*)d_ws;
  float* xg           = (float*)(ws);                         // 67108864 B
  unsigned short* qbf = (unsigned short*)(ws + 67108864);     //  8388608 B
  float* kf           = (float*)(ws + 75497472);              //   131072 B
  float* ctx          = (float*)(ws + 75628544);              // 16777216 B

  hipLaunchKernelGGL(xg_kernel,  dim3(512),  dim3(256), 0, stream, x, W_ih, b_ih, xg);
  hipLaunchKernelGGL(rbf_kernel, dim3(8192), dim3(256), 0, stream, x, prot, kf);
  hipLaunchKernelGGL(lstm_kernel, dim3(8),   dim3(512), 0, stream, xg, W_hh, b_hh, qbf);
  hipLaunchKernelGGL(attn_kernel, dim3(512), dim3(256), 0, stream, qbf, ctx);
  hipLaunchKernelGGL(mlp_kernel,  dim3(512), dim3(256), 0, stream, ctx, kf, Wc, bc, Wh, bh, out);
}

// Round 6
// 2002.828 us; speedup vs baseline: 1.4213x; 1.4213x over previous
//
#include <hip/hip_runtime.h>
#include <stdint.h>

#define B_ 16
#define S_ 2048
#define F_ 129
#define H_ 128
#define G_ 512   // 4*H

typedef float f32x4 __attribute__((ext_vector_type(4)));
typedef float f32x2 __attribute__((ext_vector_type(2)));
typedef short s16x8 __attribute__((ext_vector_type(8)));
typedef unsigned int u32x4 __attribute__((ext_vector_type(4)));
typedef _Float16 h2_t __attribute__((ext_vector_type(2)));

// LDS-only barrier: waits ds ops, does NOT drain vmcnt (global loads/stores
// stay in flight across it). __syncthreads() emits s_waitcnt vmcnt(0).
#define BAR_LDS() __asm__ volatile("s_waitcnt lgkmcnt(0)\n\ts_barrier" ::: "memory")

__device__ inline unsigned short f2bf(float f) {
  union { float f; unsigned u; } v; v.f = f;
  unsigned u = v.u;
  unsigned r = (u + 0x7FFFu + ((u >> 16) & 1u)) >> 16;
  return (unsigned short)r;
}

__device__ inline float rcp_(float x) { return __builtin_amdgcn_rcpf(x); }

__device__ inline float tanh_fast(float x) {
  float t = __expf(-2.f * fabsf(x));
  float r = (1.f - t) * rcp_(1.f + t);
  return x >= 0.f ? r : -r;
}

__device__ inline float dot2_acc(h2_t a, h2_t b, float c) {
#if __has_builtin(__builtin_amdgcn_fdot2)
  return __builtin_amdgcn_fdot2(a, b, c, false);
#else
  return c + (float)a.x * (float)b.x + (float)a.y * (float)b.y;
#endif
}

// ---------------------------------------------------------------------------
// xg[b,s,g] = sum_f x[b,s,f] * W_ih[g,f] + b_ih[g]
// ---------------------------------------------------------------------------
__global__ __launch_bounds__(256) void xg_kernel(const float* __restrict__ x,
    const float* __restrict__ W_ih, const float* __restrict__ b_ih,
    float* __restrict__ xg) {
  __shared__ __align__(16) float xs[64 * 132];
  __shared__ __align__(16) float ws[32 * 132];
  int tid = threadIdx.x;
  long R0 = (long)blockIdx.x * 64;
  for (int i = tid; i < 64 * 129; i += 256) {
    int r = i / 129, c = i - r * 129;
    xs[r * 132 + c] = x[R0 * 129 + i];
  }
  int cl = tid & 31, rg = tid >> 5;
  int r0 = rg * 8;
  for (int ch = 0; ch < 16; ++ch) {
    __syncthreads();
    for (int i = tid; i < 32 * 129; i += 256) {
      int r = i / 129, c = i - r * 129;
      ws[r * 132 + c] = W_ih[(ch * 32 + r) * 129 + c];
    }
    __syncthreads();
    int gcol = ch * 32 + cl;
    float bias = b_ih[gcol];
    float acc[8];
    #pragma unroll
    for (int rr = 0; rr < 8; ++rr) acc[rr] = bias;
    const float* wr = &ws[cl * 132];
    #pragma unroll 8
    for (int k = 0; k < 128; k += 4) {
      f32x4 w4 = *(const f32x4*)&wr[k];
      #pragma unroll
      for (int rr = 0; rr < 8; ++rr) {
        f32x4 x4 = *(const f32x4*)&xs[(r0 + rr) * 132 + k];
        acc[rr] += x4.x * w4.x + x4.y * w4.y + x4.z * w4.z + x4.w * w4.w;
      }
    }
    float wl = wr[128];
    #pragma unroll
    for (int rr = 0; rr < 8; ++rr) {
      acc[rr] += xs[(r0 + rr) * 132 + 128] * wl;
      xg[(R0 + r0 + rr) * G_ + gcol] = acc[rr];
    }
  }
}

// ---------------------------------------------------------------------------
// RBF: kf[row] = exp(-sum_f (x-p)^2), one wave per row.
// ---------------------------------------------------------------------------
__global__ __launch_bounds__(256) void rbf_kernel(const float* __restrict__ x,
    const float* __restrict__ p, float* __restrict__ kf) {
  int wave = threadIdx.x >> 6, lane = threadIdx.x & 63;
  long row = (long)blockIdx.x * 4 + wave;
  const float* xr = x + row * F_;
  const float* pr = p + row * F_;
  float ss = 0.f;
  for (int k = lane; k < F_; k += 64) { float d = xr[k] - pr[k]; ss += d * d; }
  #pragma unroll
  for (int off = 32; off; off >>= 1) ss += __shfl_xor(ss, off, 64);
  if (lane == 0) kf[row] = __expf(-ss);
}

// ---------------------------------------------------------------------------
// LSTM scan, round 6. R3 topology (16 blocks x 256 thr, 1 batch/CU, lanes
// 0-31 rows (i,g) / lanes 32-63 rows (f,o)) with the instruction-count fix
// motivated by R5's counters (issue-bound: ~500 insts/wave/step, readlane
// path bloated): the 64 v_readlane broadcasts are replaced by 16
// same-address ds_read_b128 (LDS broadcast, conflict-free per m136) into a
// fully-unrolled hw[64] register array. Plus the two R5 wins kept: BAR_LDS
// (no per-step vmcnt(0) drain of store-ack/prefetch) and the one-step
// delayed qbf store.
// ---------------------------------------------------------------------------
__global__ __launch_bounds__(256, 1) void lstm_kernel(const float* __restrict__ xg,
    const float* __restrict__ W_hh, const float* __restrict__ b_hh,
    unsigned short* __restrict__ qbf) {
  __shared__ __align__(16) unsigned int hbuf[2][64];   // h as 128 packed f16
  int tid = threadIdx.x;
  int w = tid >> 6, lane = tid & 63;
  int sub = lane >> 5;               // 0: rows (i,g)  1: rows (f,o)
  int u = (w << 5) | (lane & 31);    // h-unit 0..127
  int r0 = u + (sub << 7);           // i (sub0) / f (sub1)
  int r1 = r0 + 256;                 // g (sub0) / o (sub1)
  int b = blockIdx.x;
  h2_t W0[64], W1[64];
  const float* wr0 = &W_hh[r0 * H_];
  const float* wr1 = &W_hh[r1 * H_];
  #pragma unroll
  for (int k = 0; k < 64; ++k) {     // full unroll: constant indices -> VGPRs
    f32x2 a = *(const f32x2*)&wr0[2 * k];
    f32x2 b2 = *(const f32x2*)&wr1[2 * k];
    W0[k] = h2_t{(_Float16)a.x, (_Float16)a.y};
    W1[k] = h2_t{(_Float16)b2.x, (_Float16)b2.y};
  }
  float b0 = b_hh[r0], b1 = b_hh[r1];
  if (tid < 64) { hbuf[0][tid] = 0u; hbuf[1][tid] = 0u; }
  float c = 0.f;
  const float* xgb = xg + (long)b * S_ * G_;
  unsigned short* qb = qbf + (long)b * S_ * H_;
  float cur0 = xgb[r0], cur1 = xgb[r1];
  float nxt0 = xgb[G_ + r0], nxt1 = xgb[G_ + r1];
  unsigned short hv_prev = 0;
  __syncthreads();                   // init visibility (once)
  for (int t = 0; t < S_; ++t) {
    BAR_LDS();                       // h_{t-1} LDS writes visible; no vm drain
    // broadcast-load h_{t-1}: 16 x ds_read_b128, all lanes same address.
    unsigned int hw[64];
    const u32x4* hsrc = (const u32x4*)hbuf[(t + 1) & 1];
    #pragma unroll
    for (int i = 0; i < 16; ++i) *(u32x4*)&hw[4 * i] = hsrc[i];
    if (sub == 0 && t > 0)           // delayed store: full step in flight
      qb[(long)(t - 1) * H_ + u] = hv_prev;
    long pf = (long)((t + 2 < S_) ? t + 2 : S_ - 1) * G_;
    float nn0 = xgb[pf + r0], nn1 = xgb[pf + r1];
    float a0c[4] = {cur0 + b0, 0.f, 0.f, 0.f};
    float a1c[4] = {cur1 + b1, 0.f, 0.f, 0.f};
    #pragma unroll
    for (int k = 0; k < 64; ++k) {
      h2_t hp = __builtin_bit_cast(h2_t, hw[k]);
      a0c[k & 3] = dot2_acc(W0[k], hp, a0c[k & 3]);
      a1c[k & 3] = dot2_acc(W1[k], hp, a1c[k & 3]);
    }
    float g0 = (a0c[0] + a0c[1]) + (a0c[2] + a0c[3]);
    float g1 = (a1c[0] + a1c[1]) + (a1c[2] + a1c[3]);
    float a0 = rcp_(1.f + __expf(-g0));                       // i (sub0) / f (sub1)
    float a1 = sub ? rcp_(1.f + __expf(-g1)) : tanh_fast(g1); // g (sub0) / o (sub1)
    float fo0 = __shfl_xor(a0, 32, 64);                       // f at sub0 lanes
    float fo1 = __shfl_xor(a1, 32, 64);                       // o at sub0 lanes
    if (sub == 0) {
      c = fo0 * c + a0 * a1;
      float hv = fo1 * tanh_fast(c);
      ((_Float16*)hbuf[t & 1])[u] = (_Float16)hv;
      hv_prev = f2bf(hv);
    }
    cur0 = nxt0; cur1 = nxt1; nxt0 = nn0; nxt1 = nn1;
  }
  if (sub == 0) qb[(long)(S_ - 1) * H_ + u] = hv_prev;
}

// ---------------------------------------------------------------------------
// Flash attention, scale 1/sqrt(129). 64 Q-rows per block (4 waves x 16 rows),
// KV tiles of 64, bf16 MFMA 16x16x32. Grid = 16 batches * 32 q-tiles.
// ---------------------------------------------------------------------------
__global__ __launch_bounds__(256) void attn_kernel(const unsigned short* __restrict__ qbf,
    float* __restrict__ ctx) {
  __shared__ __align__(16) unsigned short Ks[64 * 136];
  __shared__ __align__(16) unsigned short VT[128 * 72];
  __shared__ __align__(16) unsigned short Ps[4 * 16 * 72];
  int tid = threadIdx.x;
  int lane = tid & 63, w = tid >> 6;
  int b = blockIdx.x >> 5;
  int q0 = (blockIdx.x & 31) * 64;
  const unsigned short* qb = qbf + (long)b * S_ * H_;
  int l15 = lane & 15;
  int koff = (lane >> 4) * 8;
  s16x8 qfrag[4];
  #pragma unroll
  for (int kb = 0; kb < 4; ++kb)
    qfrag[kb] = *(const s16x8*)(qb + (long)(q0 + w * 16 + l15) * H_ + kb * 32 + koff);
  f32x4 oacc[8];
  #pragma unroll
  for (int n = 0; n < 8; ++n)
    #pragma unroll
    for (int r = 0; r < 4; ++r) oacc[n][r] = 0.f;
  float mrow[4], lrow[4];
  #pragma unroll
  for (int r = 0; r < 4; ++r) { mrow[r] = -1e30f; lrow[r] = 0.f; }
  const float scale = 0.08804509063256238f;  // 1/sqrt(129)
  unsigned short* Pw = &Ps[w * 16 * 72];
  for (int t = 0; t < S_ / 64; ++t) {
    {
      int rr = tid >> 4;
      int c0 = (tid & 15) * 8;
      #pragma unroll
      for (int pch = 0; pch < 4; ++pch) {
        int r = pch * 16 + rr;
        s16x8 v = *(const s16x8*)(qb + (long)(t * 64 + r) * H_ + c0);
        *(s16x8*)(&Ks[r * 136 + c0]) = v;
        #pragma unroll
        for (int i = 0; i < 8; ++i) VT[(c0 + i) * 72 + r] = (unsigned short)v[i];
      }
    }
    __syncthreads();
    f32x4 sacc[4];
    #pragma unroll
    for (int n = 0; n < 4; ++n) {
      f32x4 acc;
      #pragma unroll
      for (int r = 0; r < 4; ++r) acc[r] = 0.f;
      #pragma unroll
      for (int kb = 0; kb < 4; ++kb) {
        s16x8 bfrag = *(const s16x8*)(&Ks[(n * 16 + l15) * 136 + kb * 32 + koff]);
        acc = __builtin_amdgcn_mfma_f32_16x16x32_bf16(qfrag[kb], bfrag, acc, 0, 0, 0);
      }
      sacc[n] = acc;
    }
    #pragma unroll
    for (int r = 0; r < 4; ++r) {
      float mx = fmaxf(fmaxf(sacc[0][r], sacc[1][r]), fmaxf(sacc[2][r], sacc[3][r]));
      #pragma unroll
      for (int m = 1; m < 16; m <<= 1) mx = fmaxf(mx, __shfl_xor(mx, m, 64));
      mx *= scale;
      float mnew = fmaxf(mrow[r], mx);
      float alpha = __expf(mrow[r] - mnew);
      mrow[r] = mnew;
      float psum = 0.f;
      #pragma unroll
      for (int n = 0; n < 4; ++n) {
        float pv = __expf(sacc[n][r] * scale - mnew);
        sacc[n][r] = pv;
        psum += pv;
      }
      #pragma unroll
      for (int m = 1; m < 16; m <<= 1) psum += __shfl_xor(psum, m, 64);
      lrow[r] = lrow[r] * alpha + psum;
      #pragma unroll
      for (int n = 0; n < 8; ++n) oacc[n][r] *= alpha;
    }
    #pragma unroll
    for (int n = 0; n < 4; ++n)
      #pragma unroll
      for (int r = 0; r < 4; ++r)
        Pw[((lane >> 4) * 4 + r) * 72 + n * 16 + l15] = f2bf(sacc[n][r]);
    __syncthreads();
    #pragma unroll
    for (int kb = 0; kb < 2; ++kb) {
      s16x8 afrag = *(const s16x8*)(&Pw[l15 * 72 + kb * 32 + koff]);
      #pragma unroll
      for (int n = 0; n < 8; ++n) {
        s16x8 bfrag = *(const s16x8*)(&VT[(n * 16 + l15) * 72 + kb * 32 + koff]);
        oacc[n] = __builtin_amdgcn_mfma_f32_16x16x32_bf16(afrag, bfrag, oacc[n], 0, 0, 0);
      }
    }
    __syncthreads();
  }
  float* cb = ctx + (long)b * S_ * H_;
  #pragma unroll
  for (int n = 0; n < 8; ++n)
    #pragma unroll
    for (int r = 0; r < 4; ++r) {
      int row = q0 + w * 16 + (lane >> 4) * 4 + r;
      cb[(long)row * H_ + n * 16 + l15] = oacc[n][r] / lrow[r];
    }
}

// ---------------------------------------------------------------------------
// Fused MLP: h0=[ctx,kf] -> 4x relu(h W^T + b) -> logits -> log_softmax.
// ---------------------------------------------------------------------------
__global__ __launch_bounds__(256) void mlp_kernel(const float* __restrict__ ctx,
    const float* __restrict__ kf, const float* __restrict__ Wc,
    const float* __restrict__ bc, const float* __restrict__ Wh,
    const float* __restrict__ bh, float* __restrict__ out) {
  __shared__ __align__(16) float hb[64 * 132];
  __shared__ __align__(16) float wc[32 * 132];
  int tid = threadIdx.x;
  long R0 = (long)blockIdx.x * 64;
  for (int i = tid; i < 64 * 128; i += 256) {
    int r = i >> 7, c = i & 127;
    hb[r * 132 + c] = ctx[(R0 + r) * H_ + c];
  }
  for (int r = tid; r < 64; r += 256) hb[r * 132 + 128] = kf[R0 + r];
  int cl = tid & 31, rg = tid >> 5, r0 = rg * 8;
  for (int l = 0; l < 4; ++l) {
    float areg[5][8];
    #pragma unroll
    for (int cc = 0; cc < 5; ++cc) {
      int cbase = cc * 32;
      int ccnt = (cc < 4) ? 32 : 1;
      __syncthreads();
      for (int i = tid; i < ccnt * 129; i += 256) {
        int r = i / 129, c = i - r * 129;
        wc[r * 132 + c] = Wc[(l * 129 + cbase + r) * 129 + c];
      }
      __syncthreads();
      if (cl < ccnt) {
        float bias = bc[l * 129 + cbase + cl];
        float acc[8];
        #pragma unroll
        for (int rr = 0; rr < 8; ++rr) acc[rr] = bias;
        const float* wr = &wc[cl * 132];
        for (int k = 0; k < 128; k += 4) {
          f32x4 w4 = *(const f32x4*)&wr[k];
          #pragma unroll
          for (int rr = 0; rr < 8; ++rr) {
            f32x4 x4 = *(const f32x4*)&hb[(r0 + rr) * 132 + k];
            acc[rr] += x4.x * w4.x + x4.y * w4.y + x4.z * w4.z + x4.w * w4.w;
          }
        }
        float wl = wr[128];
        #pragma unroll
        for (int rr = 0; rr < 8; ++rr)
          areg[cc][rr] = fmaxf(acc[rr] + hb[(r0 + rr) * 132 + 128] * wl, 0.f);
      }
    }
    __syncthreads();
    #pragma unroll
    for (int cc = 0; cc < 5; ++cc) {
      int ccnt = (cc < 4) ? 32 : 1;
      if (cl < ccnt) {
        #pragma unroll
        for (int rr = 0; rr < 8; ++rr) hb[(r0 + rr) * 132 + cc * 32 + cl] = areg[cc][rr];
      }
    }
    __syncthreads();
  }
  if (tid < 64) {
    int r = tid;
    float z0 = bh[0], z1 = bh[1];
    for (int k = 0; k < 129; ++k) {
      float h = hb[r * 132 + k];
      z0 += h * Wh[k];
      z1 += h * Wh[129 + k];
    }
    float mx = fmaxf(z0, z1);
    float lse = mx + __logf(__expf(z0 - mx) + __expf(z1 - mx));
    out[(R0 + r) * 2 + 0] = z0 - lse;
    out[(R0 + r) * 2 + 1] = z1 - lse;
  }
}

extern "C" void kernel_launch(void* const* d_in, const int* in_sizes, int n_in,
                              void* d_out, int out_size, void* d_ws, size_t ws_size,
                              hipStream_t stream) {
  const float* x    = (const float*)d_in[0];
  const float* prot = (const float*)d_in[1];
  const float* W_ih = (const float*)d_in[2];
  const float* W_hh = (const float*)d_in[3];
  const float* b_ih = (const float*)d_in[4];
  const float* b_hh = (const float*)d_in[5];
  const float* Wc   = (const float*)d_in[6];
  const float* bc   = (const float*)d_in[7];
  const float* Wh   = (const float*)d_in[8];
  const float* bh   = (const float*)d_in[9];
  float* out = (float*)d_out;
  char* ws = (char*)d_ws;
  float* xg           = (float*)(ws);                         // 67108864 B
  unsigned short* qbf = (unsigned short*)(ws + 67108864);     //  8388608 B
  float* kf           = (float*)(ws + 75497472);              //   131072 B
  float* ctx          = (float*)(ws + 75628544);              // 16777216 B

  hipLaunchKernelGGL(xg_kernel,  dim3(512),  dim3(256), 0, stream, x, W_ih, b_ih, xg);
  hipLaunchKernelGGL(rbf_kernel, dim3(8192), dim3(256), 0, stream, x, prot, kf);
  hipLaunchKernelGGL(lstm_kernel, dim3(16),  dim3(256), 0, stream, xg, W_hh, b_hh, qbf);
  hipLaunchKernelGGL(attn_kernel, dim3(512), dim3(256), 0, stream, qbf, ctx);
  hipLaunchKernelGGL(mlp_kernel,  dim3(512), dim3(256), 0, stream, ctx, kf, Wc, bc, Wh, bh, out);
}

// Round 7
// 1638.395 us; speedup vs baseline: 1.7374x; 1.2224x over previous
//
#include <hip/hip_runtime.h>
#include <stdint.h>

#define B_ 16
#define S_ 2048
#define F_ 129
#define H_ 128
#define G_ 512   // 4*H

typedef float f32x4 __attribute__((ext_vector_type(4)));
typedef float f32x2 __attribute__((ext_vector_type(2)));
typedef short s16x8 __attribute__((ext_vector_type(8)));
typedef _Float16 f16x8 __attribute__((ext_vector_type(8)));

// LDS-only barrier: waits ds ops, does NOT drain vmcnt (global loads/stores
// stay in flight across it). __syncthreads() emits s_waitcnt vmcnt(0).
#define BAR_LDS() __asm__ volatile("s_waitcnt lgkmcnt(0)\n\ts_barrier" ::: "memory")

__device__ inline unsigned short f2bf(float f) {
  union { float f; unsigned u; } v; v.f = f;
  unsigned u = v.u;
  unsigned r = (u + 0x7FFFu + ((u >> 16) & 1u)) >> 16;
  return (unsigned short)r;
}

__device__ inline float rcp_(float x) { return __builtin_amdgcn_rcpf(x); }

__device__ inline float sigmoid_fast(float x) { return rcp_(1.f + __expf(-x)); }

__device__ inline float tanh_fast(float x) {
  float t = __expf(-2.f * fabsf(x));
  float r = (1.f - t) * rcp_(1.f + t);
  return x >= 0.f ? r : -r;
}

// ---------------------------------------------------------------------------
// xg[b,s,g] = sum_f x[b,s,f] * W_ih[g,f] + b_ih[g]   (fp32, 256 CUs)
// ---------------------------------------------------------------------------
__global__ __launch_bounds__(256) void xg_kernel(const float* __restrict__ x,
    const float* __restrict__ W_ih, const float* __restrict__ b_ih,
    float* __restrict__ xg) {
  __shared__ __align__(16) float xs[64 * 132];
  __shared__ __align__(16) float ws[32 * 132];
  int tid = threadIdx.x;
  long R0 = (long)blockIdx.x * 64;
  for (int i = tid; i < 64 * 129; i += 256) {
    int r = i / 129, c = i - r * 129;
    xs[r * 132 + c] = x[R0 * 129 + i];
  }
  int cl = tid & 31, rg = tid >> 5;
  int r0 = rg * 8;
  for (int ch = 0; ch < 16; ++ch) {
    __syncthreads();
    for (int i = tid; i < 32 * 129; i += 256) {
      int r = i / 129, c = i - r * 129;
      ws[r * 132 + c] = W_ih[(ch * 32 + r) * 129 + c];
    }
    __syncthreads();
    int gcol = ch * 32 + cl;
    float bias = b_ih[gcol];
    float acc[8];
    #pragma unroll
    for (int rr = 0; rr < 8; ++rr) acc[rr] = bias;
    const float* wr = &ws[cl * 132];
    #pragma unroll 8
    for (int k = 0; k < 128; k += 4) {
      f32x4 w4 = *(const f32x4*)&wr[k];
      #pragma unroll
      for (int rr = 0; rr < 8; ++rr) {
        f32x4 x4 = *(const f32x4*)&xs[(r0 + rr) * 132 + k];
        acc[rr] += x4.x * w4.x + x4.y * w4.y + x4.z * w4.z + x4.w * w4.w;
      }
    }
    float wl = wr[128];
    #pragma unroll
    for (int rr = 0; rr < 8; ++rr) {
      acc[rr] += xs[(r0 + rr) * 132 + 128] * wl;
      xg[(R0 + r0 + rr) * G_ + gcol] = acc[rr];
    }
  }
}

// ---------------------------------------------------------------------------
// RBF: kf[row] = exp(-sum_f (x-p)^2), one wave per row.
// ---------------------------------------------------------------------------
__global__ __launch_bounds__(256) void rbf_kernel(const float* __restrict__ x,
    const float* __restrict__ p, float* __restrict__ kf) {
  int wave = threadIdx.x >> 6, lane = threadIdx.x & 63;
  long row = (long)blockIdx.x * 4 + wave;
  const float* xr = x + row * F_;
  const float* pr = p + row * F_;
  float ss = 0.f;
  for (int k = lane; k < F_; k += 64) { float d = xr[k] - pr[k]; ss += d * d; }
  #pragma unroll
  for (int off = 32; off; off >>= 1) ss += __shfl_xor(ss, off, 64);
  if (lane == 0) kf[row] = __expf(-ss);
}

// ---------------------------------------------------------------------------
// LSTM scan, round 7: MFMA formulation. 16 blocks x 512 thr (8 waves, 2/SIMD).
// gates = W_hh . h via mfma_f32_16x16x32_f16: wave w owns gate rows
// {ty*128 + 16w + (lane&15)} for ty=0..3 (4 N-tiles x 4 K-tiles = 16 MFMA).
// A-operand: ALL lanes read the same per-quad 16B of h from LDS
// (same-address ds_read_b128 broadcast, conflict-free per m136) -> every C
// row equals the true gate vector; no masking needed, epilogue is
// quad-redundant and fully lane-local (all 4 gate types of unit 16w+(lane&15)
// sit in this lane's 4 accumulators). Weights resident in 64 VGPRs as f16
// (same precision as the R3-R6 fdot2 path -> keeps absmax ~0.0039).
// One BAR_LDS per step; delayed qbf store; xg fp32 prefetch depth 2.
// Rationale: R6 plateaued at ~1600 cyc/step issue-bound on VALU; MFMA moves
// the 128-MAC/gate work to the matrix pipe (~154 cyc/SIMD/step).
// ---------------------------------------------------------------------------
__global__ __launch_bounds__(512, 2) void lstm_kernel(const float* __restrict__ xg,
    const float* __restrict__ W_hh, const float* __restrict__ b_hh,
    unsigned short* __restrict__ qbf) {
  __shared__ __align__(16) _Float16 hbuf[2][128];
  int tid = threadIdx.x;
  int w = tid >> 6, lane = tid & 63;
  int q = lane >> 4;                 // quad -> k-chunk (8 halfs)
  int n16 = lane & 15;
  int unit = (w << 4) | n16;         // h-unit 0..127 owned by this lane
  int b = blockIdx.x;
  // B-frags (weights), f16, resident: Wf[type][kb]
  f16x8 Wf[4][4];
  #pragma unroll
  for (int ty = 0; ty < 4; ++ty) {
    #pragma unroll
    for (int kb = 0; kb < 4; ++kb) {
      const float* src = &W_hh[(ty * 128 + unit) * H_ + kb * 32 + q * 8];
      f16x8 v;
      #pragma unroll
      for (int j = 0; j < 8; ++j) v[j] = (_Float16)src[j];
      Wf[ty][kb] = v;
    }
  }
  float bhh[4];
  #pragma unroll
  for (int ty = 0; ty < 4; ++ty) bhh[ty] = b_hh[ty * 128 + unit];
  if (tid < 128) ((unsigned int*)hbuf)[tid] = 0u;   // h_{-1}=0, both buffers
  float c = 0.f;
  const float* xgb = xg + (long)b * S_ * G_;
  unsigned short* qb = qbf + (long)b * S_ * H_;
  float cur[4], nxt[4];
  #pragma unroll
  for (int ty = 0; ty < 4; ++ty) {
    cur[ty] = xgb[ty * 128 + unit];
    nxt[ty] = xgb[G_ + ty * 128 + unit];
  }
  unsigned short hv_prev = 0;
  __syncthreads();                   // init visibility (once)
  for (int t = 0; t < S_; ++t) {
    BAR_LDS();                       // h_{t-1} LDS writes visible; no vm drain
    // A-frags: 4 same-address-per-quad broadcast b128 reads
    const _Float16* hsrc = hbuf[(t + 1) & 1];
    f16x8 A[4];
    #pragma unroll
    for (int kb = 0; kb < 4; ++kb)
      A[kb] = *(const f16x8*)(hsrc + kb * 32 + q * 8);
    if (lane < 16 && t > 0)          // delayed store: full step in flight
      qb[(long)(t - 1) * H_ + unit] = hv_prev;
    long pf = (long)((t + 2 < S_) ? t + 2 : S_ - 1) * G_;
    float nn[4];
    #pragma unroll
    for (int ty = 0; ty < 4; ++ty) nn[ty] = xgb[pf + ty * 128 + unit];
    // gates via MFMA: 4 chains (one per gate type) of depth 4
    f32x4 acc[4];
    #pragma unroll
    for (int ty = 0; ty < 4; ++ty) {
      f32x4 a;
      a[0] = 0.f; a[1] = 0.f; a[2] = 0.f; a[3] = 0.f;
      #pragma unroll
      for (int kb = 0; kb < 4; ++kb)
        a = __builtin_amdgcn_mfma_f32_16x16x32_f16(A[kb], Wf[ty][kb], a, 0, 0, 0);
      acc[ty] = a;
    }
    // every C row is identical (broadcast A) -> use reg 0 on every lane
    float g0 = acc[0][0] + cur[0] + bhh[0];
    float g1 = acc[1][0] + cur[1] + bhh[1];
    float g2 = acc[2][0] + cur[2] + bhh[2];
    float g3 = acc[3][0] + cur[3] + bhh[3];
    float ai = sigmoid_fast(g0);
    float af = sigmoid_fast(g1);
    float ag = tanh_fast(g2);
    float ao = sigmoid_fast(g3);
    c = af * c + ai * ag;            // quad-redundant, deterministic
    float hv = ao * tanh_fast(c);
    if (lane < 16) {                 // quad 0 publishes
      hbuf[t & 1][unit] = (_Float16)hv;
      hv_prev = f2bf(hv);
    }
    #pragma unroll
    for (int ty = 0; ty < 4; ++ty) { cur[ty] = nxt[ty]; nxt[ty] = nn[ty]; }
  }
  if (lane < 16) qb[(long)(S_ - 1) * H_ + unit] = hv_prev;
}

// ---------------------------------------------------------------------------
// Flash attention, scale 1/sqrt(129). 64 Q-rows per block (4 waves x 16 rows),
// KV tiles of 64, bf16 MFMA 16x16x32. Grid = 16 batches * 32 q-tiles.
// ---------------------------------------------------------------------------
__global__ __launch_bounds__(256) void attn_kernel(const unsigned short* __restrict__ qbf,
    float* __restrict__ ctx) {
  __shared__ __align__(16) unsigned short Ks[64 * 136];
  __shared__ __align__(16) unsigned short VT[128 * 72];
  __shared__ __align__(16) unsigned short Ps[4 * 16 * 72];
  int tid = threadIdx.x;
  int lane = tid & 63, w = tid >> 6;
  int b = blockIdx.x >> 5;
  int q0 = (blockIdx.x & 31) * 64;
  const unsigned short* qb = qbf + (long)b * S_ * H_;
  int l15 = lane & 15;
  int koff = (lane >> 4) * 8;
  s16x8 qfrag[4];
  #pragma unroll
  for (int kb = 0; kb < 4; ++kb)
    qfrag[kb] = *(const s16x8*)(qb + (long)(q0 + w * 16 + l15) * H_ + kb * 32 + koff);
  f32x4 oacc[8];
  #pragma unroll
  for (int n = 0; n < 8; ++n)
    #pragma unroll
    for (int r = 0; r < 4; ++r) oacc[n][r] = 0.f;
  float mrow[4], lrow[4];
  #pragma unroll
  for (int r = 0; r < 4; ++r) { mrow[r] = -1e30f; lrow[r] = 0.f; }
  const float scale = 0.08804509063256238f;  // 1/sqrt(129)
  unsigned short* Pw = &Ps[w * 16 * 72];
  for (int t = 0; t < S_ / 64; ++t) {
    {
      int rr = tid >> 4;
      int c0 = (tid & 15) * 8;
      #pragma unroll
      for (int pch = 0; pch < 4; ++pch) {
        int r = pch * 16 + rr;
        s16x8 v = *(const s16x8*)(qb + (long)(t * 64 + r) * H_ + c0);
        *(s16x8*)(&Ks[r * 136 + c0]) = v;
        #pragma unroll
        for (int i = 0; i < 8; ++i) VT[(c0 + i) * 72 + r] = (unsigned short)v[i];
      }
    }
    __syncthreads();
    f32x4 sacc[4];
    #pragma unroll
    for (int n = 0; n < 4; ++n) {
      f32x4 acc;
      #pragma unroll
      for (int r = 0; r < 4; ++r) acc[r] = 0.f;
      #pragma unroll
      for (int kb = 0; kb < 4; ++kb) {
        s16x8 bfrag = *(const s16x8*)(&Ks[(n * 16 + l15) * 136 + kb * 32 + koff]);
        acc = __builtin_amdgcn_mfma_f32_16x16x32_bf16(qfrag[kb], bfrag, acc, 0, 0, 0);
      }
      sacc[n] = acc;
    }
    #pragma unroll
    for (int r = 0; r < 4; ++r) {
      float mx = fmaxf(fmaxf(sacc[0][r], sacc[1][r]), fmaxf(sacc[2][r], sacc[3][r]));
      #pragma unroll
      for (int m = 1; m < 16; m <<= 1) mx = fmaxf(mx, __shfl_xor(mx, m, 64));
      mx *= scale;
      float mnew = fmaxf(mrow[r], mx);
      float alpha = __expf(mrow[r] - mnew);
      mrow[r] = mnew;
      float psum = 0.f;
      #pragma unroll
      for (int n = 0; n < 4; ++n) {
        float pv = __expf(sacc[n][r] * scale - mnew);
        sacc[n][r] = pv;
        psum += pv;
      }
      #pragma unroll
      for (int m = 1; m < 16; m <<= 1) psum += __shfl_xor(psum, m, 64);
      lrow[r] = lrow[r] * alpha + psum;
      #pragma unroll
      for (int n = 0; n < 8; ++n) oacc[n][r] *= alpha;
    }
    #pragma unroll
    for (int n = 0; n < 4; ++n)
      #pragma unroll
      for (int r = 0; r < 4; ++r)
        Pw[((lane >> 4) * 4 + r) * 72 + n * 16 + l15] = f2bf(sacc[n][r]);
    __syncthreads();
    #pragma unroll
    for (int kb = 0; kb < 2; ++kb) {
      s16x8 afrag = *(const s16x8*)(&Pw[l15 * 72 + kb * 32 + koff]);
      #pragma unroll
      for (int n = 0; n < 8; ++n) {
        s16x8 bfrag = *(const s16x8*)(&VT[(n * 16 + l15) * 72 + kb * 32 + koff]);
        oacc[n] = __builtin_amdgcn_mfma_f32_16x16x32_bf16(afrag, bfrag, oacc[n], 0, 0, 0);
      }
    }
    __syncthreads();
  }
  float* cb = ctx + (long)b * S_ * H_;
  #pragma unroll
  for (int n = 0; n < 8; ++n)
    #pragma unroll
    for (int r = 0; r < 4; ++r) {
      int row = q0 + w * 16 + (lane >> 4) * 4 + r;
      cb[(long)row * H_ + n * 16 + l15] = oacc[n][r] / lrow[r];
    }
}

// ---------------------------------------------------------------------------
// Fused MLP: h0=[ctx,kf] -> 4x relu(h W^T + b) -> logits -> log_softmax.
// ---------------------------------------------------------------------------
__global__ __launch_bounds__(256) void mlp_kernel(const float* __restrict__ ctx,
    const float* __restrict__ kf, const float* __restrict__ Wc,
    const float* __restrict__ bc, const float* __restrict__ Wh,
    const float* __restrict__ bh, float* __restrict__ out) {
  __shared__ __align__(16) float hb[64 * 132];
  __shared__ __align__(16) float wc[32 * 132];
  int tid = threadIdx.x;
  long R0 = (long)blockIdx.x * 64;
  for (int i = tid; i < 64 * 128; i += 256) {
    int r = i >> 7, c = i & 127;
    hb[r * 132 + c] = ctx[(R0 + r) * H_ + c];
  }
  for (int r = tid; r < 64; r += 256) hb[r * 132 + 128] = kf[R0 + r];
  int cl = tid & 31, rg = tid >> 5, r0 = rg * 8;
  for (int l = 0; l < 4; ++l) {
    float areg[5][8];
    #pragma unroll
    for (int cc = 0; cc < 5; ++cc) {
      int cbase = cc * 32;
      int ccnt = (cc < 4) ? 32 : 1;
      __syncthreads();
      for (int i = tid; i < ccnt * 129; i += 256) {
        int r = i / 129, c = i - r * 129;
        wc[r * 132 + c] = Wc[(l * 129 + cbase + r) * 129 + c];
      }
      __syncthreads();
      if (cl < ccnt) {
        float bias = bc[l * 129 + cbase + cl];
        float acc[8];
        #pragma unroll
        for (int rr = 0; rr < 8; ++rr) acc[rr] = bias;
        const float* wr = &wc[cl * 132];
        for (int k = 0; k < 128; k += 4) {
          f32x4 w4 = *(const f32x4*)&wr[k];
          #pragma unroll
          for (int rr = 0; rr < 8; ++rr) {
            f32x4 x4 = *(const f32x4*)&hb[(r0 + rr) * 132 + k];
            acc[rr] += x4.x * w4.x + x4.y * w4.y + x4.z * w4.z + x4.w * w4.w;
          }
        }
        float wl = wr[128];
        #pragma unroll
        for (int rr = 0; rr < 8; ++rr)
          areg[cc][rr] = fmaxf(acc[rr] + hb[(r0 + rr) * 132 + 128] * wl, 0.f);
      }
    }
    __syncthreads();
    #pragma unroll
    for (int cc = 0; cc < 5; ++cc) {
      int ccnt = (cc < 4) ? 32 : 1;
      if (cl < ccnt) {
        #pragma unroll
        for (int rr = 0; rr < 8; ++rr) hb[(r0 + rr) * 132 + cc * 32 + cl] = areg[cc][rr];
      }
    }
    __syncthreads();
  }
  if (tid < 64) {
    int r = tid;
    float z0 = bh[0], z1 = bh[1];
    for (int k = 0; k < 129; ++k) {
      float h = hb[r * 132 + k];
      z0 += h * Wh[k];
      z1 += h * Wh[129 + k];
    }
    float mx = fmaxf(z0, z1);
    float lse = mx + __logf(__expf(z0 - mx) + __expf(z1 - mx));
    out[(R0 + r) * 2 + 0] = z0 - lse;
    out[(R0 + r) * 2 + 1] = z1 - lse;
  }
}

extern "C" void kernel_launch(void* const* d_in, const int* in_sizes, int n_in,
                              void* d_out, int out_size, void* d_ws, size_t ws_size,
                              hipStream_t stream) {
  const float* x    = (const float*)d_in[0];
  const float* prot = (const float*)d_in[1];
  const float* W_ih = (const float*)d_in[2];
  const float* W_hh = (const float*)d_in[3];
  const float* b_ih = (const float*)d_in[4];
  const float* b_hh = (const float*)d_in[5];
  const float* Wc   = (const float*)d_in[6];
  const float* bc   = (const float*)d_in[7];
  const float* Wh   = (const float*)d_in[8];
  const float* bh   = (const float*)d_in[9];
  float* out = (float*)d_out;
  char* ws = (char*)d_ws;
  float* xg           = (float*)(ws);                         // 67108864 B
  unsigned short* qbf = (unsigned short*)(ws + 67108864);     //  8388608 B
  float* kf           = (float*)(ws + 75497472);              //   131072 B
  float* ctx          = (float*)(ws + 75628544);              // 16777216 B

  hipLaunchKernelGGL(xg_kernel,  dim3(512),  dim3(256), 0, stream, x, W_ih, b_ih, xg);
  hipLaunchKernelGGL(rbf_kernel, dim3(8192), dim3(256), 0, stream, x, prot, kf);
  hipLaunchKernelGGL(lstm_kernel, dim3(16),  dim3(512), 0, stream, xg, W_hh, b_hh, qbf);
  hipLaunchKernelGGL(attn_kernel, dim3(512), dim3(256), 0, stream, qbf, ctx);
  hipLaunchKernelGGL(mlp_kernel,  dim3(512), dim3(256), 0, stream, ctx, kf, Wc, bc, Wh, bh, out);
}